// Round 1
// baseline (1791.084 us; speedup 1.0000x reference)
//
#include <hip/hip_runtime.h>

// SPDUnVectorize: out[b][i][j] = x[b][triu_idx(min(i,j), max(i,j))]
// where triu_idx(i,j) = i*n - i*(i-1)/2 + (j-i) for i<=j.
// Symmetrize + half-diagonal of the reference collapses exactly to this gather.

template <int N>
__global__ __launch_bounds__(256) void spd_unvec_kernel(
    const float* __restrict__ x, float* __restrict__ out, int total_vec) {
    // One thread per float4 of output. N is a power of two (256).
    constexpr int D = N * (N + 1) / 2;
    constexpr int VPR = N / 4;  // vec4s per row
    int v = blockIdx.x * blockDim.x + threadIdx.x;
    const int stride = gridDim.x * blockDim.x;
    for (; v < total_vec; v += stride) {
        const int j0 = (v & (VPR - 1)) * 4;   // starting column
        const int t  = v / VPR;
        const int i  = t & (N - 1);           // row
        const int b  = t / N;                 // batch
        const float* __restrict__ xb = x + (size_t)b * D;
        const int rowoff_i = i * N - (i * (i - 1)) / 2;
        float vals[4];
#pragma unroll
        for (int k = 0; k < 4; ++k) {
            const int j = j0 + k;
            int idx;
            if (j >= i) {
                idx = rowoff_i + (j - i);                   // upper triangle: contiguous
            } else {
                idx = j * N - (j * (j - 1)) / 2 + (i - j);  // mirrored gather (L2-resident)
            }
            vals[k] = xb[idx];
        }
        float4 r;
        r.x = vals[0]; r.y = vals[1]; r.z = vals[2]; r.w = vals[3];
        reinterpret_cast<float4*>(out)[v] = r;
    }
}

// Generic fallback for n not equal to 256 (scalar, one thread per element).
__global__ void spd_unvec_generic(const float* __restrict__ x,
                                  float* __restrict__ out,
                                  int n, int d, long long total) {
    long long e = (long long)blockIdx.x * blockDim.x + threadIdx.x;
    const long long stride = (long long)gridDim.x * blockDim.x;
    for (; e < total; e += stride) {
        int j = (int)(e % n);
        long long t = e / n;
        int i = (int)(t % n);
        long long b = t / n;
        int lo = i < j ? i : j;
        int hi = i < j ? j : i;
        int idx = lo * n - (lo * (lo - 1)) / 2 + (hi - lo);
        out[e] = x[b * d + idx];
    }
}

extern "C" void kernel_launch(void* const* d_in, const int* in_sizes, int n_in,
                              void* d_out, int out_size, void* d_ws, size_t ws_size,
                              hipStream_t stream) {
    const float* x = (const float*)d_in[0];
    float* out = (float*)d_out;

    // Derive n: in/out = D/n^2 = (n+1)/(2n)  =>  n = 1/(2r - 1)
    const double r = (double)in_sizes[0] / (double)out_size;
    const int n = (int)(1.0 / (2.0 * r - 1.0) + 0.5);

    if (n == 256) {
        const int total_vec = out_size / 4;           // 2^26
        const int block = 256;
        const int grid = (total_vec + block - 1) / block;
        spd_unvec_kernel<256><<<grid, block, 0, stream>>>(x, out, total_vec);
    } else {
        const int d = n * (n + 1) / 2;
        const int block = 256;
        long long total = (long long)out_size;
        int grid = (int)((total + block - 1) / block);
        if (grid > 1048576) grid = 1048576;
        spd_unvec_generic<<<grid, block, 0, stream>>>(x, out, n, d, total);
    }
}